// Round 4
// baseline (331.613 us; speedup 1.0000x reference)
//
#include <hip/hip_runtime.h>
#include <math.h>

constexpr int B = 128, N = 512, HID = 512, NH = 8, DH = 64;

// ---------------------------------------------------------------------------
// K1: query = w_seed_w*seed + w_seed_b; q = w_q @ query;
//     qk[h][j] = (1/sqrt(DH)) * sum_d q[h*64+d] * w_v[(h*64+d)*HID + j]
// grid 64 (h = bid>>3, jc = bid&7), block 64
// ---------------------------------------------------------------------------
__global__ __launch_bounds__(64) void k1_qk(
    const float* __restrict__ w_q, const float* __restrict__ w_v,
    const float* __restrict__ w_sw, const float* __restrict__ w_sb,
    const float* __restrict__ seed, float* __restrict__ qk)
{
    __shared__ __align__(16) float query_s[HID];
    __shared__ float q_s[DH];
    const int t  = threadIdx.x;
    const int h  = blockIdx.x >> 3;
    const int jc = blockIdx.x & 7;
    const float sv = seed[0];
    #pragma unroll
    for (int k = 0; k < 8; ++k) {
        const int j = t * 8 + k;
        query_s[j] = w_sw[j] * sv + w_sb[j];
    }
    __syncthreads();
    {
        const float* row = w_q + (size_t)(h * DH + t) * HID;
        float acc = 0.f;
        for (int j = 0; j < HID; j += 4) {
            const float4 wv = *(const float4*)(row + j);
            acc += wv.x * query_s[j]     + wv.y * query_s[j + 1]
                 + wv.z * query_s[j + 2] + wv.w * query_s[j + 3];
        }
        q_s[t] = acc;
    }
    __syncthreads();
    {
        const int j = jc * 64 + t;
        float acc = 0.f;
        for (int d = 0; d < DH; ++d)
            acc += q_s[d] * w_v[(size_t)(h * DH + d) * HID + j];
        qk[h * HID + j] = acc * 0.125f;   // fold 1/sqrt(64)
    }
}

// ---------------------------------------------------------------------------
// KE: e[b][hh][n] = <h[b,n,:], qk[hh,:]>
// grid B*2 = 256... no: 512 blocks (b = bid>>1, half = bid&1), block 256.
// lane = row: qk addresses are lane-independent -> scalar s_load path,
// ZERO LDS. unroll 8 keeps 8 float4 global loads in flight per lane.
// Waves fully past len return (wave-uniform); boundary lanes clamp+mask.
// ---------------------------------------------------------------------------
__global__ __launch_bounds__(256) void ke_logits(
    const float* __restrict__ hbuf, const int* __restrict__ lengths,
    const float* __restrict__ qk, float* __restrict__ e_ws)
{
    const int t    = threadIdx.x;
    const int b    = blockIdx.x >> 1;
    const int half = blockIdx.x & 1;
    const int len  = lengths[b];
    const int n    = half * 256 + t;
    const int n0   = half * 256 + (t & ~63);   // first row of this wave
    if (n0 >= len) return;                     // wave-uniform exit

    const int nn = min(n, len - 1);            // clamp keeps flow uniform
    const float* row = hbuf + ((size_t)b * N + nn) * HID;
    float acc[NH];
    #pragma unroll
    for (int hh = 0; hh < NH; ++hh) acc[hh] = 0.f;

    #pragma unroll 8
    for (int j = 0; j < HID; j += 4) {
        const float4 hv = *(const float4*)(row + j);
        #pragma unroll
        for (int hh = 0; hh < NH; ++hh) {
            const float* qp = qk + hh * HID + j;   // lane-invariant -> s_load
            acc[hh] += hv.x * qp[0] + hv.y * qp[1]
                     + hv.z * qp[2] + hv.w * qp[3];
        }
    }
    if (n < len) {
        #pragma unroll
        for (int hh = 0; hh < NH; ++hh)
            e_ws[(size_t)(b * NH + hh) * N + n] = acc[hh];
    }
}

// ---------------------------------------------------------------------------
// KS: masked softmax per (b,hh); writes alpha (head-major, zeros past len)
// and interleaved al_t[b][n][hh] for KC's scalar-load path.
// grid B, block 256 (wave w -> heads w, w+4).
// ---------------------------------------------------------------------------
__global__ __launch_bounds__(256) void ks_softmax(
    const float* __restrict__ e_ws, const int* __restrict__ lengths,
    float* __restrict__ alpha, float* __restrict__ al_t)
{
    const int b    = blockIdx.x;
    const int lane = threadIdx.x & 63;
    const int w    = threadIdx.x >> 6;
    const int len  = lengths[b];
    for (int hh = w; hh < NH; hh += 4) {
        const float* e = e_ws + (size_t)(b * NH + hh) * N;
        float ev[8];
        float m = -3.0e38f;
        #pragma unroll
        for (int it = 0; it < 8; ++it) {
            const int n = it * 64 + lane;
            ev[it] = (n < len) ? e[n] : -3.0e38f;
            m = fmaxf(m, ev[it]);
        }
        #pragma unroll
        for (int off = 32; off; off >>= 1)
            m = fmaxf(m, __shfl_xor(m, off, 64));
        float s = 0.f;
        #pragma unroll
        for (int it = 0; it < 8; ++it) {
            ev[it] = __expf(ev[it] - m);
            s += ev[it];
        }
        #pragma unroll
        for (int off = 32; off; off >>= 1)
            s += __shfl_xor(s, off, 64);
        const float inv = 1.f / s;
        float* ao = alpha + (size_t)(b * NH + hh) * N;
        float* at = al_t + (size_t)b * N * NH + hh;
        #pragma unroll
        for (int it = 0; it < 8; ++it) {
            const int n   = it * 64 + lane;
            const float v = (n < len) ? ev[it] * inv : 0.f;
            ao[n]      = v;
            at[n * NH] = v;
        }
    }
}

// ---------------------------------------------------------------------------
// KC: partial ctx over a 64-row chunk, split again by row parity g.
// grid B*8 (b = bid>>3, c = bid&7), block 256 (g = t>>7, colquad cq = t&127).
// Each lane loads float4 (16B); wave covers 1KB contiguous per row.
// Alpha from al_t at block-uniform addresses -> s_load_dwordx8. ZERO LDS.
// Partials always stored (zero if chunk past len) for KD's fixed sum.
// ---------------------------------------------------------------------------
__global__ __launch_bounds__(256) void kc_ctx(
    const float* __restrict__ hbuf, const int* __restrict__ lengths,
    const float* __restrict__ al_t, float* __restrict__ ctxp)
{
    const int t   = threadIdx.x;
    const int b   = blockIdx.x >> 3;
    const int c   = blockIdx.x & 7;
    const int n0  = c * 64;
    const int g   = t >> 7;               // wave-uniform (waves 0,1 -> 0; 2,3 -> 1)
    const int cq  = t & 127;
    const int len = lengths[b];
    const int nend = min(len - n0, 64);

    float4 acc[NH];
    #pragma unroll
    for (int hh = 0; hh < NH; ++hh) { acc[hh].x = acc[hh].y = acc[hh].z = acc[hh].w = 0.f; }

    const float* hb = hbuf + ((size_t)b * N + n0) * HID + cq * 4;
    const float* ap = al_t + ((size_t)b * N + n0) * NH;   // block-uniform
    #pragma unroll 4
    for (int ln = g; ln < nend; ln += 2) {
        const float4 hv = *(const float4*)(hb + (size_t)ln * HID);
        const float* a = ap + ln * NH;                    // uniform -> s_load_dwordx8
        acc[0].x += a[0] * hv.x; acc[0].y += a[0] * hv.y; acc[0].z += a[0] * hv.z; acc[0].w += a[0] * hv.w;
        acc[1].x += a[1] * hv.x; acc[1].y += a[1] * hv.y; acc[1].z += a[1] * hv.z; acc[1].w += a[1] * hv.w;
        acc[2].x += a[2] * hv.x; acc[2].y += a[2] * hv.y; acc[2].z += a[2] * hv.z; acc[2].w += a[2] * hv.w;
        acc[3].x += a[3] * hv.x; acc[3].y += a[3] * hv.y; acc[3].z += a[3] * hv.z; acc[3].w += a[3] * hv.w;
        acc[4].x += a[4] * hv.x; acc[4].y += a[4] * hv.y; acc[4].z += a[4] * hv.z; acc[4].w += a[4] * hv.w;
        acc[5].x += a[5] * hv.x; acc[5].y += a[5] * hv.y; acc[5].z += a[5] * hv.z; acc[5].w += a[5] * hv.w;
        acc[6].x += a[6] * hv.x; acc[6].y += a[6] * hv.y; acc[6].z += a[6] * hv.z; acc[6].w += a[6] * hv.w;
        acc[7].x += a[7] * hv.x; acc[7].y += a[7] * hv.y; acc[7].z += a[7] * hv.z; acc[7].w += a[7] * hv.w;
    }
    float* cp = ctxp + (size_t)(((b * 8 + c) * 2 + g) * NH) * HID + cq * 4;
    #pragma unroll
    for (int hh = 0; hh < NH; ++hh)
        *(float4*)(cp + (size_t)hh * HID) = acc[hh];
}

// ---------------------------------------------------------------------------
// KD: ctx = sum of 16 partials; out_h[p] = <ctx[p>>6], w_v[p,:]>;
//     out[b,i] = <out_h, w_o[i,:]>. grid B, block 256.
// ---------------------------------------------------------------------------
__global__ __launch_bounds__(256) void kd_out(
    const float* __restrict__ ctxp, const float* __restrict__ w_v,
    const float* __restrict__ w_o, float* __restrict__ out)
{
    __shared__ __align__(16) float ctx_s[NH * HID];
    __shared__ __align__(16) float oh_s[HID];
    const int t = threadIdx.x;
    const int b = blockIdx.x;
    const float* p0 = ctxp + (size_t)(b * 16) * NH * HID;
    for (int i = t; i < NH * HID; i += 256) {
        float s = 0.f;
        #pragma unroll
        for (int cc = 0; cc < 16; ++cc) s += p0[(size_t)cc * NH * HID + i];
        ctx_s[i] = s;
    }
    __syncthreads();
    #pragma unroll
    for (int rep = 0; rep < 2; ++rep) {
        const int p  = rep * 256 + t;
        const int hh = p >> 6;
        const float* wrow = w_v + (size_t)p * HID;
        float acc = 0.f;
        for (int j = 0; j < HID; j += 4) {
            const float4 wv = *(const float4*)(wrow + j);
            const float4 cv = *(const float4*)&ctx_s[hh * HID + j];
            acc += wv.x * cv.x + wv.y * cv.y + wv.z * cv.z + wv.w * cv.w;
        }
        oh_s[p] = acc;
    }
    __syncthreads();
    #pragma unroll
    for (int rep = 0; rep < 2; ++rep) {
        const int i = rep * 256 + t;
        const float* wrow = w_o + (size_t)i * HID;
        float acc = 0.f;
        for (int j = 0; j < HID; j += 4) {
            const float4 wv = *(const float4*)(wrow + j);
            const float4 ov = *(const float4*)&oh_s[j];
            acc += wv.x * ov.x + wv.y * ov.y + wv.z * ov.z + wv.w * ov.w;
        }
        out[(size_t)b * HID + i] = acc;
    }
}

// ---------------------------------------------------------------------------
extern "C" void kernel_launch(void* const* d_in, const int* in_sizes, int n_in,
                              void* d_out, int out_size, void* d_ws, size_t ws_size,
                              hipStream_t stream) {
    const float* h     = (const float*)d_in[0];
    const int*   lens  = (const int*)  d_in[1];
    const float* w_q   = (const float*)d_in[2];
    // d_in[3] = w_k: dead compute in the reference, intentionally unused
    const float* w_v   = (const float*)d_in[4];
    const float* w_o   = (const float*)d_in[5];
    const float* w_sw  = (const float*)d_in[6];
    const float* w_sb  = (const float*)d_in[7];
    const float* seed  = (const float*)d_in[8];

    float* out   = (float*)d_out;            // [B, HID]
    float* alpha = out + (size_t)B * HID;    // [B, NH, N, 1]

    // ws (floats): qk[4096] | e[524288] | al_t[524288] | ctxp[B*16*NH*HID]
    float* ws   = (float*)d_ws;
    float* qk   = ws;
    float* e_ws = qk + NH * HID;
    float* al_t = e_ws + (size_t)B * NH * N;
    float* ctxp = al_t + (size_t)B * N * NH;

    hipLaunchKernelGGL(k1_qk,      dim3(64),    dim3(64),  0, stream,
                       w_q, w_v, w_sw, w_sb, seed, qk);
    hipLaunchKernelGGL(ke_logits,  dim3(B * 2), dim3(256), 0, stream,
                       h, lens, qk, e_ws);
    hipLaunchKernelGGL(ks_softmax, dim3(B),     dim3(256), 0, stream,
                       e_ws, lens, alpha, al_t);
    hipLaunchKernelGGL(kc_ctx,     dim3(B * 8), dim3(256), 0, stream,
                       h, lens, al_t, ctxp);
    hipLaunchKernelGGL(kd_out,     dim3(B),     dim3(256), 0, stream,
                       ctxp, w_v, w_o, out);
}

// Round 5
// 305.082 us; speedup vs baseline: 1.0870x; 1.0870x over previous
//
#include <hip/hip_runtime.h>
#include <math.h>

constexpr int B = 128, N = 512, HID = 512, NH = 8, DH = 64;

// ---------------------------------------------------------------------------
// K1: query = w_seed_w*seed + w_seed_b; q = w_q @ query;
//     qk[h][j] = (1/sqrt(DH)) * sum_d q[h*64+d] * w_v[(h*64+d)*HID + j]
// grid 64 (h = bid>>3, jc = bid&7), block 64
// ---------------------------------------------------------------------------
__global__ __launch_bounds__(64) void k1_qk(
    const float* __restrict__ w_q, const float* __restrict__ w_v,
    const float* __restrict__ w_sw, const float* __restrict__ w_sb,
    const float* __restrict__ seed, float* __restrict__ qk)
{
    __shared__ __align__(16) float query_s[HID];
    __shared__ float q_s[DH];
    const int t  = threadIdx.x;
    const int h  = blockIdx.x >> 3;
    const int jc = blockIdx.x & 7;
    const float sv = seed[0];
    #pragma unroll
    for (int k = 0; k < 8; ++k) {
        const int j = t * 8 + k;
        query_s[j] = w_sw[j] * sv + w_sb[j];
    }
    __syncthreads();
    {
        const float* row = w_q + (size_t)(h * DH + t) * HID;
        float acc = 0.f;
        for (int j = 0; j < HID; j += 4) {
            const float4 wv = *(const float4*)(row + j);
            acc += wv.x * query_s[j]     + wv.y * query_s[j + 1]
                 + wv.z * query_s[j + 2] + wv.w * query_s[j + 3];
        }
        q_s[t] = acc;
    }
    __syncthreads();
    {
        const int j = jc * 64 + t;
        float acc = 0.f;
        for (int d = 0; d < DH; ++d)
            acc += q_s[d] * w_v[(size_t)(h * DH + d) * HID + j];
        qk[h * HID + j] = acc * 0.125f;   // fold 1/sqrt(64)
    }
}

// ---------------------------------------------------------------------------
// KE: e[b][hh][n] = <h[b,n,:], qk[hh,:]>   — wave-per-row, fully coalesced.
// grid B*8 (b = bid>>3, 64-row chunk c = bid&7), block 256 (4 waves).
// Lane l loads row[l*4] and row[256+l*4]: each instr covers 1KB contiguous.
// qk preloaded to registers (8 heads x 8 cols per lane). Reduction: head-
// folding butterfly (8 vals -> 1 in 3 fold steps + 3 xor steps, 17 shuffles).
// ---------------------------------------------------------------------------
__global__ __launch_bounds__(256) void ke_logits(
    const float* __restrict__ hbuf, const int* __restrict__ lengths,
    const float* __restrict__ qk, float* __restrict__ e_ws)
{
    const int t = threadIdx.x;
    const int l = t & 63;
    const int w = t >> 6;
    const int b = blockIdx.x >> 3;
    const int c = blockIdx.x & 7;
    const int n0 = c * 64;
    const int len = lengths[b];
    if (n0 >= len) return;                    // block-uniform exit

    // per-lane qk slice: cols [l*4, l*4+4) and [256+l*4, 256+l*4+4)
    float4 qlo[NH], qhi[NH];
    #pragma unroll
    for (int hh = 0; hh < NH; ++hh) {
        qlo[hh] = *(const float4*)&qk[hh * HID + l * 4];
        qhi[hh] = *(const float4*)&qk[hh * HID + 256 + l * 4];
    }

    const int nmax = min(n0 + 64, len);
    const float* hb = hbuf + (size_t)b * N * HID;
    // lane->head map for the folded reduction result
    const int hh_out = ((l & 1) << 2) | (l & 2) | ((l >> 2) & 1);

    for (int n = n0 + w; n < nmax; n += 4) {
        const float* row = hb + (size_t)n * HID;
        const float4 h0 = *(const float4*)(row + l * 4);        // 1KB/wave
        const float4 h1 = *(const float4*)(row + 256 + l * 4);  // 1KB/wave
        float v[NH];
        #pragma unroll
        for (int hh = 0; hh < NH; ++hh)
            v[hh] = h0.x * qlo[hh].x + h0.y * qlo[hh].y
                  + h0.z * qlo[hh].z + h0.w * qlo[hh].w
                  + h1.x * qhi[hh].x + h1.y * qhi[hh].y
                  + h1.z * qhi[hh].z + h1.w * qhi[hh].w;

        // fold 8 -> 4 (xor 1): even lanes keep heads 0-3, odd heads 4-7
        #pragma unroll
        for (int i = 0; i < 4; ++i) {
            const float ax = __shfl_xor(v[i], 1, 64);
            const float bx = __shfl_xor(v[i + 4], 1, 64);
            v[i] = (l & 1) ? (v[i + 4] + bx) : (v[i] + ax);
        }
        // fold 4 -> 2 (xor 2)
        #pragma unroll
        for (int i = 0; i < 2; ++i) {
            const float ax = __shfl_xor(v[i], 2, 64);
            const float bx = __shfl_xor(v[i + 2], 2, 64);
            v[i] = (l & 2) ? (v[i + 2] + bx) : (v[i] + ax);
        }
        // fold 2 -> 1 (xor 4)
        {
            const float ax = __shfl_xor(v[0], 4, 64);
            const float bx = __shfl_xor(v[1], 4, 64);
            v[0] = (l & 4) ? (v[1] + bx) : (v[0] + ax);
        }
        // cross-group sums
        v[0] += __shfl_xor(v[0], 8, 64);
        v[0] += __shfl_xor(v[0], 16, 64);
        v[0] += __shfl_xor(v[0], 32, 64);

        if (l < 8)
            e_ws[(size_t)(b * NH + hh_out) * N + n] = v[0];
    }
}

// ---------------------------------------------------------------------------
// KS: masked softmax per (b,hh); writes alpha (head-major, zeros past len)
// and interleaved al_t[b][n][hh]. grid B*2 (b=bid>>1, head-group=bid&1),
// block 256: wave w -> head grp*4+w.
// ---------------------------------------------------------------------------
__global__ __launch_bounds__(256) void ks_softmax(
    const float* __restrict__ e_ws, const int* __restrict__ lengths,
    float* __restrict__ alpha, float* __restrict__ al_t)
{
    const int b    = blockIdx.x >> 1;
    const int grp  = blockIdx.x & 1;
    const int lane = threadIdx.x & 63;
    const int hh   = grp * 4 + (threadIdx.x >> 6);
    const int len  = lengths[b];

    const float* e = e_ws + (size_t)(b * NH + hh) * N;
    float ev[8];
    float m = -3.0e38f;
    #pragma unroll
    for (int it = 0; it < 8; ++it) {
        const int n = it * 64 + lane;
        ev[it] = (n < len) ? e[n] : -3.0e38f;
        m = fmaxf(m, ev[it]);
    }
    #pragma unroll
    for (int off = 32; off; off >>= 1)
        m = fmaxf(m, __shfl_xor(m, off, 64));
    float s = 0.f;
    #pragma unroll
    for (int it = 0; it < 8; ++it) {
        ev[it] = __expf(ev[it] - m);
        s += ev[it];
    }
    #pragma unroll
    for (int off = 32; off; off >>= 1)
        s += __shfl_xor(s, off, 64);
    const float inv = 1.f / s;
    float* ao = alpha + (size_t)(b * NH + hh) * N;
    float* at = al_t + (size_t)b * N * NH + hh;
    #pragma unroll
    for (int it = 0; it < 8; ++it) {
        const int n   = it * 64 + lane;
        const float v = (n < len) ? ev[it] * inv : 0.f;
        ao[n]      = v;
        at[n * NH] = v;
    }
}

// ---------------------------------------------------------------------------
// KC: partial ctx over a 64-row chunk, split by row parity g.
// grid B*8 (b = bid>>3, c = bid&7), block 256 (g = t>>7, colquad cq = t&127).
// Lane float4 loads: each 2-wave group covers 2KB contiguous per row.
// Alpha from al_t at block-uniform addresses -> scalar loads. ZERO LDS.
// ---------------------------------------------------------------------------
__global__ __launch_bounds__(256) void kc_ctx(
    const float* __restrict__ hbuf, const int* __restrict__ lengths,
    const float* __restrict__ al_t, float* __restrict__ ctxp)
{
    const int t   = threadIdx.x;
    const int b   = blockIdx.x >> 3;
    const int c   = blockIdx.x & 7;
    const int n0  = c * 64;
    const int g   = t >> 7;               // wave-uniform
    const int cq  = t & 127;
    const int len = lengths[b];
    const int nend = min(len - n0, 64);

    float4 acc[NH];
    #pragma unroll
    for (int hh = 0; hh < NH; ++hh) { acc[hh].x = acc[hh].y = acc[hh].z = acc[hh].w = 0.f; }

    const float* hb = hbuf + ((size_t)b * N + n0) * HID + cq * 4;
    const float* ap = al_t + ((size_t)b * N + n0) * NH;   // block-uniform
    #pragma unroll 4
    for (int ln = g; ln < nend; ln += 2) {
        const float4 hv = *(const float4*)(hb + (size_t)ln * HID);
        const float* a = ap + ln * NH;                    // uniform -> s_load
        acc[0].x += a[0] * hv.x; acc[0].y += a[0] * hv.y; acc[0].z += a[0] * hv.z; acc[0].w += a[0] * hv.w;
        acc[1].x += a[1] * hv.x; acc[1].y += a[1] * hv.y; acc[1].z += a[1] * hv.z; acc[1].w += a[1] * hv.w;
        acc[2].x += a[2] * hv.x; acc[2].y += a[2] * hv.y; acc[2].z += a[2] * hv.z; acc[2].w += a[2] * hv.w;
        acc[3].x += a[3] * hv.x; acc[3].y += a[3] * hv.y; acc[3].z += a[3] * hv.z; acc[3].w += a[3] * hv.w;
        acc[4].x += a[4] * hv.x; acc[4].y += a[4] * hv.y; acc[4].z += a[4] * hv.z; acc[4].w += a[4] * hv.w;
        acc[5].x += a[5] * hv.x; acc[5].y += a[5] * hv.y; acc[5].z += a[5] * hv.z; acc[5].w += a[5] * hv.w;
        acc[6].x += a[6] * hv.x; acc[6].y += a[6] * hv.y; acc[6].z += a[6] * hv.z; acc[6].w += a[6] * hv.w;
        acc[7].x += a[7] * hv.x; acc[7].y += a[7] * hv.y; acc[7].z += a[7] * hv.z; acc[7].w += a[7] * hv.w;
    }
    float* cp = ctxp + (size_t)(((b * 8 + c) * 2 + g) * NH) * HID + cq * 4;
    #pragma unroll
    for (int hh = 0; hh < NH; ++hh)
        *(float4*)(cp + (size_t)hh * HID) = acc[hh];
}

// ---------------------------------------------------------------------------
// KD: ctx = sum of 16 partials; out_h[p] = <ctx[p>>6], w_v[p,:]>;
//     out[b,i] = <out_h, w_o[i,:]>. grid B, block 256.
// ---------------------------------------------------------------------------
__global__ __launch_bounds__(256) void kd_out(
    const float* __restrict__ ctxp, const float* __restrict__ w_v,
    const float* __restrict__ w_o, float* __restrict__ out)
{
    __shared__ __align__(16) float ctx_s[NH * HID];
    __shared__ __align__(16) float oh_s[HID];
    const int t = threadIdx.x;
    const int b = blockIdx.x;
    const float* p0 = ctxp + (size_t)(b * 16) * NH * HID;
    for (int i = t; i < NH * HID; i += 256) {
        float s = 0.f;
        #pragma unroll
        for (int cc = 0; cc < 16; ++cc) s += p0[(size_t)cc * NH * HID + i];
        ctx_s[i] = s;
    }
    __syncthreads();
    #pragma unroll
    for (int rep = 0; rep < 2; ++rep) {
        const int p  = rep * 256 + t;
        const int hh = p >> 6;
        const float* wrow = w_v + (size_t)p * HID;
        float acc = 0.f;
        for (int j = 0; j < HID; j += 4) {
            const float4 wv = *(const float4*)(wrow + j);
            const float4 cv = *(const float4*)&ctx_s[hh * HID + j];
            acc += wv.x * cv.x + wv.y * cv.y + wv.z * cv.z + wv.w * cv.w;
        }
        oh_s[p] = acc;
    }
    __syncthreads();
    #pragma unroll
    for (int rep = 0; rep < 2; ++rep) {
        const int i = rep * 256 + t;
        const float* wrow = w_o + (size_t)i * HID;
        float acc = 0.f;
        for (int j = 0; j < HID; j += 4) {
            const float4 wv = *(const float4*)(wrow + j);
            const float4 ov = *(const float4*)&oh_s[j];
            acc += wv.x * ov.x + wv.y * ov.y + wv.z * ov.z + wv.w * ov.w;
        }
        out[(size_t)b * HID + i] = acc;
    }
}

// ---------------------------------------------------------------------------
extern "C" void kernel_launch(void* const* d_in, const int* in_sizes, int n_in,
                              void* d_out, int out_size, void* d_ws, size_t ws_size,
                              hipStream_t stream) {
    const float* h     = (const float*)d_in[0];
    const int*   lens  = (const int*)  d_in[1];
    const float* w_q   = (const float*)d_in[2];
    // d_in[3] = w_k: dead compute in the reference, intentionally unused
    const float* w_v   = (const float*)d_in[4];
    const float* w_o   = (const float*)d_in[5];
    const float* w_sw  = (const float*)d_in[6];
    const float* w_sb  = (const float*)d_in[7];
    const float* seed  = (const float*)d_in[8];

    float* out   = (float*)d_out;            // [B, HID]
    float* alpha = out + (size_t)B * HID;    // [B, NH, N, 1]

    // ws (floats): qk[4096] | e[524288] | al_t[524288] | ctxp[B*16*NH*HID]
    float* ws   = (float*)d_ws;
    float* qk   = ws;
    float* e_ws = qk + NH * HID;
    float* al_t = e_ws + (size_t)B * NH * N;
    float* ctxp = al_t + (size_t)B * N * NH;

    hipLaunchKernelGGL(k1_qk,      dim3(64),    dim3(64),  0, stream,
                       w_q, w_v, w_sw, w_sb, seed, qk);
    hipLaunchKernelGGL(ke_logits,  dim3(B * 8), dim3(256), 0, stream,
                       h, lens, qk, e_ws);
    hipLaunchKernelGGL(ks_softmax, dim3(B * 2), dim3(256), 0, stream,
                       e_ws, lens, alpha, al_t);
    hipLaunchKernelGGL(kc_ctx,     dim3(B * 8), dim3(256), 0, stream,
                       h, lens, al_t, ctxp);
    hipLaunchKernelGGL(kd_out,     dim3(B),     dim3(256), 0, stream,
                       ctxp, w_v, w_o, out);
}